// Round 1
// baseline (914.661 us; speedup 1.0000x reference)
//
#include <hip/hip_runtime.h>

#define NVOX 300000
#define K27 27

typedef __attribute__((ext_vector_type(8))) __bf16 bf16x8;
typedef __attribute__((ext_vector_type(8))) unsigned short ushort8;
typedef __attribute__((ext_vector_type(4))) float f32x4;

__device__ inline unsigned short f2bf(float x){
  unsigned int u = __float_as_uint(x);
  unsigned int r = (u + 0x7FFFu + ((u >> 16) & 1u)) >> 16;   // RNE
  return (unsigned short)r;
}

// ---- pack bw [4][27][32][32] f32 -> MFMA B-fragment order [cv][k][half][lane][8] bf16 ----
__global__ void pack_w_kernel(const float* __restrict__ bw, unsigned short* __restrict__ pw){
  int t = blockIdx.x*256 + threadIdx.x;
  if (t >= 4*K27*2*64) return;
  int l  = t & 63;
  int h  = (t >> 6) & 1;
  int k  = (t >> 7) % K27;
  int cv = t / (128*K27);
  int g = l >> 4, r16 = l & 15;
  ushort8 o;
  #pragma unroll
  for (int i = 0; i < 8; ++i){
    int c  = g*8 + i;          // input channel (K dim)
    int oc = h*16 + r16;       // output channel (N dim)
    o[i] = f2bf(bw[(((cv*K27 + k)*32) + c)*32 + oc]);
  }
  *reinterpret_cast<ushort8*>(pw + t*8) = o;
}

// ---- conv0: [N,3] x [27,3,32] -> trunk [N,32] f32, + stats ----
__global__ void __launch_bounds__(256) conv0_kernel(
    const float* __restrict__ feats, const int* __restrict__ nbr,
    const float* __restrict__ w0, float* __restrict__ out,
    float* __restrict__ stats){
  __shared__ int   snbr[256*K27];
  __shared__ float trans[256*33];
  __shared__ float sstat[64];
  int tid  = threadIdx.x;
  int base = blockIdx.x * 256;
  for (int i = tid; i < 256*K27; i += 256){
    int v = base + i / K27;
    snbr[i] = (v < NVOX) ? nbr[base*K27 + i] : NVOX;
  }
  if (tid < 64) sstat[tid] = 0.f;
  __syncthreads();

  float acc[32];
  #pragma unroll
  for (int d = 0; d < 32; ++d) acc[d] = 0.f;
  for (int k = 0; k < K27; ++k){
    int j = snbr[tid*K27 + k];
    float f0 = 0.f, f1 = 0.f, f2 = 0.f;
    if (j < NVOX){
      f0 = feats[j*3+0]; f1 = feats[j*3+1]; f2 = feats[j*3+2];
    }
    const float* wk = w0 + k*96;   // uniform -> s_load
    #pragma unroll
    for (int d = 0; d < 32; ++d)
      acc[d] += f0*wk[d] + f1*wk[32+d] + f2*wk[64+d];
  }

  #pragma unroll
  for (int d = 0; d < 32; ++d) trans[tid*33 + d] = acc[d];
  __syncthreads();

  { // per-block stats partials
    int ch = tid & 31, grp = tid >> 5;
    float ps = 0.f, pss = 0.f;
    #pragma unroll 4
    for (int rr = 0; rr < 32; ++rr){
      float v = trans[(grp*32 + rr)*33 + ch];
      ps += v; pss += v*v;
    }
    atomicAdd(&sstat[ch], ps);
    atomicAdd(&sstat[32+ch], pss);
  }

  // coalesced f32 writes from LDS
  #pragma unroll
  for (int it = 0; it < 8; ++it){
    int row = it*32 + (tid >> 3);
    int c0  = (tid & 7)*4;
    if (base + row < NVOX){
      float4 v;
      v.x = trans[row*33 + c0+0];
      v.y = trans[row*33 + c0+1];
      v.z = trans[row*33 + c0+2];
      v.w = trans[row*33 + c0+3];
      *reinterpret_cast<float4*>(out + (size_t)(base+row)*32 + c0) = v;
    }
  }
  __syncthreads();
  if (tid < 64) atomicAdd(&stats[(blockIdx.x & 63)*64 + tid], sstat[tid]);
}

// ---- BN finalize: reduce 64 slots -> scale/bias (bnp[0..31]=scale, [32..63]=bias) ----
__global__ void bn_finalize_kernel(const float* __restrict__ stats,
                                   const float* __restrict__ g, const float* __restrict__ b,
                                   float* __restrict__ bnp){
  int t = threadIdx.x;
  if (t >= 32) return;
  float s = 0.f, q = 0.f;
  for (int i = 0; i < 64; ++i){ s += stats[i*64 + t]; q += stats[i*64 + 32 + t]; }
  float inv = 1.0f / (float)NVOX;
  float mu  = s * inv;
  float var = q * inv - mu*mu;
  float sc  = g[t] * rsqrtf(var + 1e-4f);
  bnp[t]      = sc;
  bnp[32 + t] = b[t] - mu*sc;
}

// ---- activation: bf16 act[row] = relu(trunk*scale+bias); row N zeroed (gather sentinel) ----
__global__ void act_kernel(const float* __restrict__ trunk, const float* __restrict__ bnp,
                           unsigned short* __restrict__ act){
  int t = blockIdx.x*256 + threadIdx.x;
  if (t >= (NVOX+1)*4) return;
  int row = t >> 2, part = t & 3;
  ushort8 o;
  if (row < NVOX){
    const float* p = trunk + (size_t)row*32 + part*8;
    #pragma unroll
    for (int i = 0; i < 8; ++i){
      float v = p[i]*bnp[part*8 + i] + bnp[32 + part*8 + i];
      v = fmaxf(v, 0.f);
      o[i] = f2bf(v);
    }
  } else {
    #pragma unroll
    for (int i = 0; i < 8; ++i) o[i] = 0;
  }
  *reinterpret_cast<ushort8*>(act + (size_t)row*32 + part*8) = o;
}

// ---- MFMA conv 32->32 over 27 taps; optional in-place residual add; fused stats ----
template<bool RES>
__global__ void __launch_bounds__(256) conv_mfma_kernel(
    const unsigned short* __restrict__ act, const int* __restrict__ nbr,
    const unsigned short* __restrict__ pw, float* __restrict__ trunk,
    float* __restrict__ stats){
  __shared__ int   snbr[256*K27];
  __shared__ float sstat[64];
  int tid  = threadIdx.x;
  int base = blockIdx.x*256;
  for (int i = tid; i < 256*K27; i += 256){
    int v = base + i / K27;
    snbr[i] = (v < NVOX) ? nbr[base*K27 + i] : NVOX;
  }
  if (tid < 64) sstat[tid] = 0.f;
  __syncthreads();

  int l = tid & 63, w = tid >> 6;
  int g = l >> 4, r16 = l & 15;
  const int vb = w*64;

  f32x4 acc[4][2];
  #pragma unroll
  for (int t = 0; t < 4; ++t)
    #pragma unroll
    for (int h = 0; h < 2; ++h)
      acc[t][h] = (f32x4){0.f, 0.f, 0.f, 0.f};

  for (int k = 0; k < K27; ++k){
    bf16x8 b0 = *reinterpret_cast<const bf16x8*>(pw + (k*2 + 0)*512 + l*8);
    bf16x8 b1 = *reinterpret_cast<const bf16x8*>(pw + (k*2 + 1)*512 + l*8);
    bf16x8 a[4];
    #pragma unroll
    for (int t = 0; t < 4; ++t){
      int j = snbr[(vb + t*16 + r16)*K27 + k];          // sentinel N -> zero row
      a[t] = *reinterpret_cast<const bf16x8*>(act + (size_t)j*32 + g*8);
    }
    #pragma unroll
    for (int t = 0; t < 4; ++t){
      acc[t][0] = __builtin_amdgcn_mfma_f32_16x16x32_bf16(a[t], b0, acc[t][0], 0, 0, 0);
      acc[t][1] = __builtin_amdgcn_mfma_f32_16x16x32_bf16(a[t], b1, acc[t][1], 0, 0, 0);
    }
  }

  // epilogue: residual add, store, per-channel stats (D: col=l&15, row=(l>>4)*4+reg)
  float s0[2] = {0.f, 0.f}, s1[2] = {0.f, 0.f};
  #pragma unroll
  for (int t = 0; t < 4; ++t){
    #pragma unroll
    for (int r = 0; r < 4; ++r){
      int row = base + vb + t*16 + g*4 + r;
      if (row < NVOX){
        #pragma unroll
        for (int h = 0; h < 2; ++h){
          float v = acc[t][h][r];
          float* p = trunk + (size_t)row*32 + h*16 + r16;
          if (RES) v += *p;
          *p = v;
          s0[h] += v; s1[h] += v*v;
        }
      }
    }
  }
  #pragma unroll
  for (int h = 0; h < 2; ++h){
    s0[h] += __shfl_xor(s0[h], 16);
    s0[h] += __shfl_xor(s0[h], 32);
    s1[h] += __shfl_xor(s1[h], 16);
    s1[h] += __shfl_xor(s1[h], 32);
  }
  if (l < 16){
    atomicAdd(&sstat[r16],        s0[0]);
    atomicAdd(&sstat[32 + r16],   s1[0]);
    atomicAdd(&sstat[16 + r16],   s0[1]);
    atomicAdd(&sstat[48 + r16],   s1[1]);
  }
  __syncthreads();
  if (tid < 64) atomicAdd(&stats[(blockIdx.x & 63)*64 + tid], sstat[tid]);
}

// ---- heads: f = relu(bn(trunk)); y[20], emb[32], offset[1] ----
__global__ void __launch_bounds__(256) heads_kernel(
    const float* __restrict__ trunk, const float* __restrict__ bnp,
    const float* __restrict__ w_cls, const float* __restrict__ b_cls,
    const float* __restrict__ w_fe,  const float* __restrict__ b_fe,
    const float* __restrict__ w_le,  const float* __restrict__ b_le,
    const float* __restrict__ w_fr,  const float* __restrict__ b_fr,
    const float* __restrict__ w_lr,  const float* __restrict__ b_lr,
    float* __restrict__ out){
  int n = blockIdx.x*256 + threadIdx.x;
  if (n >= NVOX) return;
  float f[32];
  const float* p = trunk + (size_t)n*32;
  #pragma unroll
  for (int c = 0; c < 32; ++c){
    float v = p[c]*bnp[c] + bnp[32 + c];
    f[c] = fmaxf(v, 0.f);
  }
  #pragma unroll
  for (int d = 0; d < 20; ++d){
    float y = b_cls[d];
    #pragma unroll
    for (int c = 0; c < 32; ++c) y += f[c]*w_cls[c*20 + d];
    out[(size_t)n*20 + d] = y;
  }
  float t1[32];
  #pragma unroll
  for (int d = 0; d < 32; ++d){
    float v = b_fe[d];
    #pragma unroll
    for (int c = 0; c < 32; ++c) v += f[c]*w_fe[c*32 + d];
    t1[d] = v;
  }
  float* out_e = out + (size_t)NVOX*20;
  #pragma unroll
  for (int d = 0; d < 32; ++d){
    float v = b_le[d];
    #pragma unroll
    for (int c = 0; c < 32; ++c) v += t1[c]*w_le[c*32 + d];
    out_e[(size_t)n*32 + d] = v;
  }
  float o = b_lr[0];
  #pragma unroll
  for (int d = 0; d < 32; ++d){
    float v = b_fr[d];
    #pragma unroll
    for (int c = 0; c < 32; ++c) v += f[c]*w_fr[c*32 + d];
    o += v*w_lr[d];
  }
  out[(size_t)NVOX*52 + n] = 1.f/(1.f + __expf(-o));
}

extern "C" void kernel_launch(void* const* d_in, const int* in_sizes, int n_in,
                              void* d_out, int out_size, void* d_ws, size_t ws_size,
                              hipStream_t stream){
  const float* features = (const float*)d_in[0];
  const int*   nbr      = (const int*)  d_in[1];
  const float* w0       = (const float*)d_in[2];
  const float* bw       = (const float*)d_in[3];
  const float* bg       = (const float*)d_in[4];
  const float* bb       = (const float*)d_in[5];
  const float* gf       = (const float*)d_in[6];
  const float* bf       = (const float*)d_in[7];
  const float* w_cls    = (const float*)d_in[8];
  const float* b_cls    = (const float*)d_in[9];
  const float* w_fe     = (const float*)d_in[10];
  const float* b_fe     = (const float*)d_in[11];
  const float* w_le     = (const float*)d_in[12];
  const float* b_le     = (const float*)d_in[13];
  const float* w_fr     = (const float*)d_in[14];
  const float* b_fr     = (const float*)d_in[15];
  const float* w_lr     = (const float*)d_in[16];
  const float* b_lr     = (const float*)d_in[17];
  float* out = (float*)d_out;

  char* ws = (char*)d_ws;
  float*          trunkA = (float*)(ws);                       // [N][32] f32
  float*          trunkH = (float*)(ws + 38400000);            // [N][32] f32
  unsigned short* actB   = (unsigned short*)(ws + 76800000);   // [(N+1)][32] bf16
  unsigned short* pw     = (unsigned short*)(ws + 96000128);   // packed weights
  float*          stats  = (float*)(ws + 96221312);            // 5 x 64 slots x 64
  float*          bnp    = (float*)(ws + 96303232);            // 5 x 64

  hipMemsetAsync(stats, 0, 5*64*64*sizeof(float), stream);
  pack_w_kernel<<<(4*K27*2*64 + 255)/256, 256, 0, stream>>>(bw, pw);

  const int NB = (NVOX + 255)/256;
  const int NA = ((NVOX+1)*4 + 255)/256;

  conv0_kernel<<<NB, 256, 0, stream>>>(features, nbr, w0, trunkA, stats + 0*4096);
  bn_finalize_kernel<<<1, 64, 0, stream>>>(stats + 0*4096, bg +  0, bb +  0, bnp +   0);
  act_kernel<<<NA, 256, 0, stream>>>(trunkA, bnp +   0, actB);
  conv_mfma_kernel<false><<<NB, 256, 0, stream>>>(actB, nbr, pw + 0*27648, trunkH, stats + 1*4096);
  bn_finalize_kernel<<<1, 64, 0, stream>>>(stats + 1*4096, bg + 32, bb + 32, bnp +  64);
  act_kernel<<<NA, 256, 0, stream>>>(trunkH, bnp +  64, actB);
  conv_mfma_kernel<true ><<<NB, 256, 0, stream>>>(actB, nbr, pw + 1*27648, trunkA, stats + 2*4096);
  bn_finalize_kernel<<<1, 64, 0, stream>>>(stats + 2*4096, bg + 64, bb + 64, bnp + 128);
  act_kernel<<<NA, 256, 0, stream>>>(trunkA, bnp + 128, actB);
  conv_mfma_kernel<false><<<NB, 256, 0, stream>>>(actB, nbr, pw + 2*27648, trunkH, stats + 3*4096);
  bn_finalize_kernel<<<1, 64, 0, stream>>>(stats + 3*4096, bg + 96, bb + 96, bnp + 192);
  act_kernel<<<NA, 256, 0, stream>>>(trunkH, bnp + 192, actB);
  conv_mfma_kernel<true ><<<NB, 256, 0, stream>>>(actB, nbr, pw + 3*27648, trunkA, stats + 4*4096);
  bn_finalize_kernel<<<1, 64, 0, stream>>>(stats + 4*4096, gf, bf, bnp + 256);
  heads_kernel<<<NB, 256, 0, stream>>>(trunkA, bnp + 256,
                                       w_cls, b_cls, w_fe, b_fe, w_le, b_le,
                                       w_fr, b_fr, w_lr, b_lr, out);
}

// Round 2
// 503.604 us; speedup vs baseline: 1.8162x; 1.8162x over previous
//
#include <hip/hip_runtime.h>

#define NVOX 300000
#define K27 27

typedef __attribute__((ext_vector_type(8))) __bf16 bf16x8;
typedef __attribute__((ext_vector_type(8))) unsigned short ushort8;
typedef __attribute__((ext_vector_type(4))) float f32x4;

__device__ inline unsigned short f2bf(float x){
  unsigned int u = __float_as_uint(x);
  unsigned int r = (u + 0x7FFFu + ((u >> 16) & 1u)) >> 16;   // RNE
  return (unsigned short)r;
}

// ---- pack bw [4][27][32][32] f32 -> MFMA B-fragment order [cv][k][half][lane][8] bf16 ----
__global__ void pack_w_kernel(const float* __restrict__ bw, unsigned short* __restrict__ pw){
  int t = blockIdx.x*256 + threadIdx.x;
  if (t >= 4*K27*2*64) return;
  int l  = t & 63;
  int h  = (t >> 6) & 1;
  int k  = (t >> 7) % K27;
  int cv = t / (128*K27);
  int g = l >> 4, r16 = l & 15;
  ushort8 o;
  #pragma unroll
  for (int i = 0; i < 8; ++i){
    int c  = g*8 + i;          // input channel (K dim)
    int oc = h*16 + r16;       // output channel (N dim)
    o[i] = f2bf(bw[(((cv*K27 + k)*32) + c)*32 + oc]);
  }
  *reinterpret_cast<ushort8*>(pw + t*8) = o;
}

// ---- pack head weights: B1 = [w_fe | w_fr | w_cls | pad] (6 halves), B2 = w_le (2 halves);
//      bcat[96] = [b_fe | b_fr | b_cls | 0] ----
__global__ void pack_hw_kernel(const float* __restrict__ w_cls, const float* __restrict__ b_cls,
                               const float* __restrict__ w_fe,  const float* __restrict__ b_fe,
                               const float* __restrict__ w_le,
                               const float* __restrict__ w_fr,  const float* __restrict__ b_fr,
                               unsigned short* __restrict__ pwh, float* __restrict__ bcat){
  int t = blockIdx.x*512 + threadIdx.x;
  if (t < 96){
    float v = 0.f;
    if (t < 32)      v = b_fe[t];
    else if (t < 64) v = b_fr[t-32];
    else if (t < 84) v = b_cls[t-64];
    bcat[t] = v;
  }
  if (t >= 8*64) return;
  int l = t & 63, f = t >> 6;
  int g = l >> 4, r16 = l & 15;
  ushort8 o;
  #pragma unroll
  for (int i = 0; i < 8; ++i){
    int k = g*8 + i;
    float v;
    if (f < 6){
      int col = f*16 + r16;
      if (col < 32)      v = w_fe[k*32 + col];
      else if (col < 64) v = w_fr[k*32 + (col-32)];
      else { int c = col - 64; v = (c < 20) ? w_cls[k*20 + c] : 0.f; }
    } else {
      int col = (f-6)*16 + r16;
      v = w_le[k*32 + col];
    }
    o[i] = f2bf(v);
  }
  *reinterpret_cast<ushort8*>(pwh + t*8) = o;
}

// ---- conv0: [N,3] x [27,3,32] -> trunk [N,32] f32, + stats ----
__global__ void __launch_bounds__(256) conv0_kernel(
    const float* __restrict__ feats, const int* __restrict__ nbr,
    const float* __restrict__ w0, float* __restrict__ out,
    float* __restrict__ stats){
  __shared__ int   snbr[256*K27];
  __shared__ float trans[256*33];
  __shared__ float sstat[64];
  int tid  = threadIdx.x;
  int base = blockIdx.x * 256;
  for (int i = tid; i < 256*K27; i += 256){
    int v = base + i / K27;
    snbr[i] = (v < NVOX) ? nbr[base*K27 + i] : NVOX;
  }
  if (tid < 64) sstat[tid] = 0.f;
  __syncthreads();

  float acc[32];
  #pragma unroll
  for (int d = 0; d < 32; ++d) acc[d] = 0.f;
  for (int k = 0; k < K27; ++k){
    int j = snbr[tid*K27 + k];
    float f0 = 0.f, f1 = 0.f, f2 = 0.f;
    if (j < NVOX){
      f0 = feats[j*3+0]; f1 = feats[j*3+1]; f2 = feats[j*3+2];
    }
    const float* wk = w0 + k*96;   // uniform -> s_load
    #pragma unroll
    for (int d = 0; d < 32; ++d)
      acc[d] += f0*wk[d] + f1*wk[32+d] + f2*wk[64+d];
  }

  #pragma unroll
  for (int d = 0; d < 32; ++d) trans[tid*33 + d] = acc[d];
  __syncthreads();

  { // per-block stats partials
    int ch = tid & 31, grp = tid >> 5;
    float ps = 0.f, pss = 0.f;
    #pragma unroll 4
    for (int rr = 0; rr < 32; ++rr){
      float v = trans[(grp*32 + rr)*33 + ch];
      ps += v; pss += v*v;
    }
    atomicAdd(&sstat[ch], ps);
    atomicAdd(&sstat[32+ch], pss);
  }

  // coalesced f32 writes from LDS
  #pragma unroll
  for (int it = 0; it < 8; ++it){
    int row = it*32 + (tid >> 3);
    int c0  = (tid & 7)*4;
    if (base + row < NVOX){
      float4 v;
      v.x = trans[row*33 + c0+0];
      v.y = trans[row*33 + c0+1];
      v.z = trans[row*33 + c0+2];
      v.w = trans[row*33 + c0+3];
      *reinterpret_cast<float4*>(out + (size_t)(base+row)*32 + c0) = v;
    }
  }
  __syncthreads();
  if (tid < 64) atomicAdd(&stats[(blockIdx.x & 63)*64 + tid], sstat[tid]);
}

// ---- BN finalize: reduce 64 slots -> scale/bias (bnp[0..31]=scale, [32..63]=bias) ----
__global__ void bn_finalize_kernel(const float* __restrict__ stats,
                                   const float* __restrict__ g, const float* __restrict__ b,
                                   float* __restrict__ bnp){
  int t = threadIdx.x;
  if (t >= 32) return;
  float s = 0.f, q = 0.f;
  for (int i = 0; i < 64; ++i){ s += stats[i*64 + t]; q += stats[i*64 + 32 + t]; }
  float inv = 1.0f / (float)NVOX;
  float mu  = s * inv;
  float var = q * inv - mu*mu;
  float sc  = g[t] * rsqrtf(var + 1e-4f);
  bnp[t]      = sc;
  bnp[32 + t] = b[t] - mu*sc;
}

// ---- activation: bf16 act[row] = relu(trunk*scale+bias); row N zeroed (gather sentinel) ----
__global__ void act_kernel(const float* __restrict__ trunk, const float* __restrict__ bnp,
                           unsigned short* __restrict__ act){
  int t = blockIdx.x*256 + threadIdx.x;
  if (t >= (NVOX+1)*4) return;
  int row = t >> 2, part = t & 3;
  ushort8 o;
  if (row < NVOX){
    const float* p = trunk + (size_t)row*32 + part*8;
    #pragma unroll
    for (int i = 0; i < 8; ++i){
      float v = p[i]*bnp[part*8 + i] + bnp[32 + part*8 + i];
      v = fmaxf(v, 0.f);
      o[i] = f2bf(v);
    }
  } else {
    #pragma unroll
    for (int i = 0; i < 8; ++i) o[i] = 0;
  }
  *reinterpret_cast<ushort8*>(act + (size_t)row*32 + part*8) = o;
}

// ---- MFMA conv 32->32 over 27 taps; optional in-place residual add; fused stats ----
template<bool RES>
__global__ void __launch_bounds__(256) conv_mfma_kernel(
    const unsigned short* __restrict__ act, const int* __restrict__ nbr,
    const unsigned short* __restrict__ pw, float* __restrict__ trunk,
    float* __restrict__ stats){
  __shared__ int   snbr[256*K27];
  __shared__ float sstat[64];
  int tid  = threadIdx.x;
  int base = blockIdx.x*256;
  for (int i = tid; i < 256*K27; i += 256){
    int v = base + i / K27;
    snbr[i] = (v < NVOX) ? nbr[base*K27 + i] : NVOX;
  }
  if (tid < 64) sstat[tid] = 0.f;
  __syncthreads();

  int l = tid & 63, w = tid >> 6;
  int g = l >> 4, r16 = l & 15;
  const int vb = w*64;

  f32x4 acc[4][2];
  #pragma unroll
  for (int t = 0; t < 4; ++t)
    #pragma unroll
    for (int h = 0; h < 2; ++h)
      acc[t][h] = (f32x4){0.f, 0.f, 0.f, 0.f};

  for (int k = 0; k < K27; ++k){
    bf16x8 b0 = *reinterpret_cast<const bf16x8*>(pw + (k*2 + 0)*512 + l*8);
    bf16x8 b1 = *reinterpret_cast<const bf16x8*>(pw + (k*2 + 1)*512 + l*8);
    bf16x8 a[4];
    #pragma unroll
    for (int t = 0; t < 4; ++t){
      int j = snbr[(vb + t*16 + r16)*K27 + k];          // sentinel N -> zero row
      a[t] = *reinterpret_cast<const bf16x8*>(act + (size_t)j*32 + g*8);
    }
    #pragma unroll
    for (int t = 0; t < 4; ++t){
      acc[t][0] = __builtin_amdgcn_mfma_f32_16x16x32_bf16(a[t], b0, acc[t][0], 0, 0, 0);
      acc[t][1] = __builtin_amdgcn_mfma_f32_16x16x32_bf16(a[t], b1, acc[t][1], 0, 0, 0);
    }
  }

  // epilogue: residual add, store, per-channel stats (D: col=l&15, row=(l>>4)*4+reg)
  float s0[2] = {0.f, 0.f}, s1[2] = {0.f, 0.f};
  #pragma unroll
  for (int t = 0; t < 4; ++t){
    #pragma unroll
    for (int r = 0; r < 4; ++r){
      int row = base + vb + t*16 + g*4 + r;
      if (row < NVOX){
        #pragma unroll
        for (int h = 0; h < 2; ++h){
          float v = acc[t][h][r];
          float* p = trunk + (size_t)row*32 + h*16 + r16;
          if (RES) v += *p;
          *p = v;
          s0[h] += v; s1[h] += v*v;
        }
      }
    }
  }
  #pragma unroll
  for (int h = 0; h < 2; ++h){
    s0[h] += __shfl_xor(s0[h], 16);
    s0[h] += __shfl_xor(s0[h], 32);
    s1[h] += __shfl_xor(s1[h], 16);
    s1[h] += __shfl_xor(s1[h], 32);
  }
  if (l < 16){
    atomicAdd(&sstat[r16],        s0[0]);
    atomicAdd(&sstat[32 + r16],   s1[0]);
    atomicAdd(&sstat[16 + r16],   s0[1]);
    atomicAdd(&sstat[48 + r16],   s1[1]);
  }
  __syncthreads();
  if (tid < 64) atomicAdd(&stats[(blockIdx.x & 63)*64 + tid], sstat[tid]);
}

// ---- MFMA heads: f=relu(bn(trunk)); y = f@Wcls+b, emb = (f@Wfe+b)@Wle+b, off = sig((f@Wfr+b)@wlr+b) ----
__global__ void __launch_bounds__(256) heads_mfma_kernel(
    const float* __restrict__ trunk, const float* __restrict__ bnp,
    const unsigned short* __restrict__ pwh, const float* __restrict__ bcat,
    const float* __restrict__ b_le, const float* __restrict__ w_lr, const float* __restrict__ b_lr,
    float* __restrict__ out){
  __shared__ float lds[4][16][33];
  int tid = threadIdx.x;
  int l = tid & 63, w = tid >> 6;
  int g = l >> 4, r16 = l & 15;
  int base = blockIdx.x*256 + w*64;

  // B fragments (per-lane)
  bf16x8 B1[6], B2[2];
  #pragma unroll
  for (int f = 0; f < 6; ++f)
    B1[f] = *reinterpret_cast<const bf16x8*>(pwh + f*512 + l*8);
  #pragma unroll
  for (int h = 0; h < 2; ++h)
    B2[h] = *reinterpret_cast<const bf16x8*>(pwh + (6+h)*512 + l*8);

  // bn params for this lane's 8 channels (ch = g*8 + i)
  float4 sc0 = *reinterpret_cast<const float4*>(bnp + g*8);
  float4 sc1 = *reinterpret_cast<const float4*>(bnp + g*8 + 4);
  float4 bi0 = *reinterpret_cast<const float4*>(bnp + 32 + g*8);
  float4 bi1 = *reinterpret_cast<const float4*>(bnp + 32 + g*8 + 4);
  float wlr0 = w_lr[r16], wlr1 = w_lr[16 + r16];
  float blr  = b_lr[0];
  float bc0  = bcat[r16],      bc1  = bcat[16 + r16];   // b_fe
  float bc2  = bcat[32 + r16], bc3  = bcat[48 + r16];   // b_fr
  float bc4  = bcat[64 + r16], bc5  = bcat[80 + r16];   // b_cls (padded)
  float ble0 = b_le[r16],      ble1 = b_le[16 + r16];

  float* out_e = out + (size_t)NVOX*20;
  float* out_o = out + (size_t)NVOX*52;

  for (int t = 0; t < 4; ++t){
    int arow = base + t*16 + r16;
    float4 fa = {0.f,0.f,0.f,0.f}, fb = {0.f,0.f,0.f,0.f};
    if (arow < NVOX){
      fa = *reinterpret_cast<const float4*>(trunk + (size_t)arow*32 + g*8);
      fb = *reinterpret_cast<const float4*>(trunk + (size_t)arow*32 + g*8 + 4);
    }
    ushort8 au;
    au[0] = f2bf(fmaxf(fa.x*sc0.x + bi0.x, 0.f));
    au[1] = f2bf(fmaxf(fa.y*sc0.y + bi0.y, 0.f));
    au[2] = f2bf(fmaxf(fa.z*sc0.z + bi0.z, 0.f));
    au[3] = f2bf(fmaxf(fa.w*sc0.w + bi0.w, 0.f));
    au[4] = f2bf(fmaxf(fb.x*sc1.x + bi1.x, 0.f));
    au[5] = f2bf(fmaxf(fb.y*sc1.y + bi1.y, 0.f));
    au[6] = f2bf(fmaxf(fb.z*sc1.z + bi1.z, 0.f));
    au[7] = f2bf(fmaxf(fb.w*sc1.w + bi1.w, 0.f));
    bf16x8 a = __builtin_bit_cast(bf16x8, au);

    f32x4 acc[6];
    #pragma unroll
    for (int j = 0; j < 6; ++j){
      acc[j] = (f32x4){0.f,0.f,0.f,0.f};
      acc[j] = __builtin_amdgcn_mfma_f32_16x16x32_bf16(a, B1[j], acc[j], 0, 0, 0);
    }

    // ---- y head (cols 64..95 -> cls 0..31, valid < 20) ----
    #pragma unroll
    for (int r = 0; r < 4; ++r){
      int orow = base + t*16 + g*4 + r;
      if (orow < NVOX){
        out[(size_t)orow*20 + r16] = acc[4][r] + bc4;           // cls 0..15
        if (r16 < 4)
          out[(size_t)orow*20 + 16 + r16] = acc[5][r] + bc5;    // cls 16..19
      }
    }

    // ---- offset head: t2 = acc[2],acc[3] (+bias), dot w_lr, reduce over 16-lane group ----
    float part[4];
    #pragma unroll
    for (int r = 0; r < 4; ++r)
      part[r] = (acc[2][r] + bc2)*wlr0 + (acc[3][r] + bc3)*wlr1;
    #pragma unroll
    for (int r = 0; r < 4; ++r){
      part[r] += __shfl_xor(part[r], 1);
      part[r] += __shfl_xor(part[r], 2);
      part[r] += __shfl_xor(part[r], 4);
      part[r] += __shfl_xor(part[r], 8);
    }
    if (r16 == 0){
      #pragma unroll
      for (int r = 0; r < 4; ++r){
        int orow = base + t*16 + g*4 + r;
        if (orow < NVOX)
          out_o[orow] = 1.f/(1.f + __expf(-(part[r] + blr)));
      }
    }

    // ---- emb: t1 (acc[0],acc[1]) -> LDS (C layout) -> A layout -> MFMA with w_le ----
    #pragma unroll
    for (int r = 0; r < 4; ++r){
      lds[w][g*4 + r][r16]      = acc[0][r] + bc0;
      lds[w][g*4 + r][16 + r16] = acc[1][r] + bc1;
    }
    __syncthreads();
    ushort8 a2u;
    #pragma unroll
    for (int i = 0; i < 8; ++i)
      a2u[i] = f2bf(lds[w][r16][g*8 + i]);
    bf16x8 a2 = __builtin_bit_cast(bf16x8, a2u);
    f32x4 e0 = (f32x4){0.f,0.f,0.f,0.f}, e1 = (f32x4){0.f,0.f,0.f,0.f};
    e0 = __builtin_amdgcn_mfma_f32_16x16x32_bf16(a2, B2[0], e0, 0, 0, 0);
    e1 = __builtin_amdgcn_mfma_f32_16x16x32_bf16(a2, B2[1], e1, 0, 0, 0);
    #pragma unroll
    for (int r = 0; r < 4; ++r){
      int orow = base + t*16 + g*4 + r;
      if (orow < NVOX){
        out_e[(size_t)orow*32 + r16]      = e0[r] + ble0;
        out_e[(size_t)orow*32 + 16 + r16] = e1[r] + ble1;
      }
    }
    __syncthreads();
  }
}

extern "C" void kernel_launch(void* const* d_in, const int* in_sizes, int n_in,
                              void* d_out, int out_size, void* d_ws, size_t ws_size,
                              hipStream_t stream){
  const float* features = (const float*)d_in[0];
  const int*   nbr      = (const int*)  d_in[1];
  const float* w0       = (const float*)d_in[2];
  const float* bw       = (const float*)d_in[3];
  const float* bg       = (const float*)d_in[4];
  const float* bb       = (const float*)d_in[5];
  const float* gf       = (const float*)d_in[6];
  const float* bf       = (const float*)d_in[7];
  const float* w_cls    = (const float*)d_in[8];
  const float* b_cls    = (const float*)d_in[9];
  const float* w_fe     = (const float*)d_in[10];
  const float* b_fe     = (const float*)d_in[11];
  const float* w_le     = (const float*)d_in[12];
  const float* b_le     = (const float*)d_in[13];
  const float* w_fr     = (const float*)d_in[14];
  const float* b_fr     = (const float*)d_in[15];
  const float* w_lr     = (const float*)d_in[16];
  const float* b_lr     = (const float*)d_in[17];
  float* out = (float*)d_out;

  char* ws = (char*)d_ws;
  float*          trunkA = (float*)(ws);                       // [N][32] f32
  float*          trunkH = (float*)(ws + 38400000);            // [N][32] f32
  unsigned short* actB   = (unsigned short*)(ws + 76800000);   // [(N+1)][32] bf16
  unsigned short* pw     = (unsigned short*)(ws + 96000128);   // packed conv weights
  float*          stats  = (float*)(ws + 96221312);            // 5 x 64 slots x 64
  float*          bnp    = (float*)(ws + 96303232);            // 5 x 64
  unsigned short* pwh    = (unsigned short*)(ws + 96304512);   // packed head weights (8 frags)
  float*          bcat   = (float*)(ws + 96312704);            // 96 f32 head biases

  hipMemsetAsync(stats, 0, 5*64*64*sizeof(float), stream);
  pack_w_kernel<<<(4*K27*2*64 + 255)/256, 256, 0, stream>>>(bw, pw);
  pack_hw_kernel<<<1, 512, 0, stream>>>(w_cls, b_cls, w_fe, b_fe, w_le, w_fr, b_fr, pwh, bcat);

  const int NB = (NVOX + 255)/256;
  const int NA = ((NVOX+1)*4 + 255)/256;

  conv0_kernel<<<NB, 256, 0, stream>>>(features, nbr, w0, trunkA, stats + 0*4096);
  bn_finalize_kernel<<<1, 64, 0, stream>>>(stats + 0*4096, bg +  0, bb +  0, bnp +   0);
  act_kernel<<<NA, 256, 0, stream>>>(trunkA, bnp +   0, actB);
  conv_mfma_kernel<false><<<NB, 256, 0, stream>>>(actB, nbr, pw + 0*27648, trunkH, stats + 1*4096);
  bn_finalize_kernel<<<1, 64, 0, stream>>>(stats + 1*4096, bg + 32, bb + 32, bnp +  64);
  act_kernel<<<NA, 256, 0, stream>>>(trunkH, bnp +  64, actB);
  conv_mfma_kernel<true ><<<NB, 256, 0, stream>>>(actB, nbr, pw + 1*27648, trunkA, stats + 2*4096);
  bn_finalize_kernel<<<1, 64, 0, stream>>>(stats + 2*4096, bg + 64, bb + 64, bnp + 128);
  act_kernel<<<NA, 256, 0, stream>>>(trunkA, bnp + 128, actB);
  conv_mfma_kernel<false><<<NB, 256, 0, stream>>>(actB, nbr, pw + 2*27648, trunkH, stats + 3*4096);
  bn_finalize_kernel<<<1, 64, 0, stream>>>(stats + 3*4096, bg + 96, bb + 96, bnp + 192);
  act_kernel<<<NA, 256, 0, stream>>>(trunkH, bnp + 192, actB);
  conv_mfma_kernel<true ><<<NB, 256, 0, stream>>>(actB, nbr, pw + 3*27648, trunkA, stats + 4*4096);
  bn_finalize_kernel<<<1, 64, 0, stream>>>(stats + 4*4096, gf, bf, bnp + 256);
  heads_mfma_kernel<<<NB, 256, 0, stream>>>(trunkA, bnp + 256, pwh, bcat,
                                            b_le, w_lr, b_lr, out);
}

// Round 4
// 452.797 us; speedup vs baseline: 2.0200x; 1.1122x over previous
//
#include <hip/hip_runtime.h>

#define NVOX 300000
#define K27 27

typedef __attribute__((ext_vector_type(8))) __bf16 bf16x8;
typedef __attribute__((ext_vector_type(8))) unsigned short ushort8;
typedef __attribute__((ext_vector_type(4))) float f32x4;

__device__ inline unsigned short f2bf(float x){
  unsigned int u = __float_as_uint(x);
  unsigned int r = (u + 0x7FFFu + ((u >> 16) & 1u)) >> 16;   // RNE
  return (unsigned short)r;
}

// ---- pack conv weights ----
// bw [4][27][32][32] f32 -> pw: [cv][k][half][lane][8] bf16  (13824 frag-threads)
// w0 [27][3][32] f32 (K padded to 108=4kb*32) -> pw0: [kb][half][lane][8] bf16 (512 threads)
__global__ void pack_w_kernel(const float* __restrict__ bw, const float* __restrict__ w0,
                              unsigned short* __restrict__ pw, unsigned short* __restrict__ pw0){
  int t = blockIdx.x*256 + threadIdx.x;
  if (t < 4*K27*2*64){
    int l  = t & 63;
    int h  = (t >> 6) & 1;
    int k  = (t >> 7) % K27;
    int cv = t / (128*K27);
    int g = l >> 4, r16 = l & 15;
    ushort8 o;
    #pragma unroll
    for (int i = 0; i < 8; ++i){
      int c  = g*8 + i;          // input channel (K dim)
      int oc = h*16 + r16;       // output channel (N dim)
      o[i] = f2bf(bw[(((cv*K27 + k)*32) + c)*32 + oc]);
    }
    *reinterpret_cast<ushort8*>(pw + t*8) = o;
    return;
  }
  int u = t - 4*K27*2*64;
  if (u >= 4*2*64) return;
  int l  = u & 63;
  int h  = (u >> 6) & 1;
  int kb = u >> 7;
  int g = l >> 4, r16 = l & 15;
  int col = h*16 + r16;
  ushort8 o;
  #pragma unroll
  for (int i = 0; i < 8; ++i){
    int k   = kb*32 + g*8 + i;
    int tap = k >> 2, ch = k & 3;
    float v = (tap < K27 && ch < 3) ? w0[(tap*3 + ch)*32 + col] : 0.f;
    o[i] = f2bf(v);
  }
  *reinterpret_cast<ushort8*>(pw0 + u*8) = o;
}

// ---- pack head weights: B1 = [w_fe | w_fr | w_cls | pad] (6 halves), B2 = w_le (2 halves);
//      bcat[96] = [b_fe | b_fr | b_cls | 0] ----
__global__ void pack_hw_kernel(const float* __restrict__ w_cls, const float* __restrict__ b_cls,
                               const float* __restrict__ w_fe,  const float* __restrict__ b_fe,
                               const float* __restrict__ w_le,
                               const float* __restrict__ w_fr,  const float* __restrict__ b_fr,
                               unsigned short* __restrict__ pwh, float* __restrict__ bcat){
  int t = blockIdx.x*512 + threadIdx.x;
  if (t < 96){
    float v = 0.f;
    if (t < 32)      v = b_fe[t];
    else if (t < 64) v = b_fr[t-32];
    else if (t < 84) v = b_cls[t-64];
    bcat[t] = v;
  }
  if (t >= 8*64) return;
  int l = t & 63, f = t >> 6;
  int g = l >> 4, r16 = l & 15;
  ushort8 o;
  #pragma unroll
  for (int i = 0; i < 8; ++i){
    int k = g*8 + i;
    float v;
    if (f < 6){
      int col = f*16 + r16;
      if (col < 32)      v = w_fe[k*32 + col];
      else if (col < 64) v = w_fr[k*32 + (col-32)];
      else { int c = col - 64; v = (c < 20) ? w_cls[k*20 + c] : 0.f; }
    } else {
      int col = (f-6)*16 + r16;
      v = w_le[k*32 + col];
    }
    o[i] = f2bf(v);
  }
  *reinterpret_cast<ushort8*>(pwh + t*8) = o;
}

// ---- pre-pad features: [N,3] f32 -> [N+1][4] f32 (w=0, row N = 0 sentinel) ----
__global__ void prepad_kernel(const float* __restrict__ feats, float4* __restrict__ fpad){
  int row = blockIdx.x*256 + threadIdx.x;
  if (row > NVOX) return;
  float4 v = {0.f, 0.f, 0.f, 0.f};
  if (row < NVOX){
    v.x = feats[row*3+0]; v.y = feats[row*3+1]; v.z = feats[row*3+2];
  }
  fpad[row] = v;
}

// ---- conv0 via MFMA: K=108 (27 taps x 4ch padded), gathers float4/tap ----
__global__ void __launch_bounds__(256) conv0_mfma_kernel(
    const float4* __restrict__ fpad, const int* __restrict__ nbr,
    const unsigned short* __restrict__ pw0, float* __restrict__ trunk,
    float* __restrict__ stats){
  __shared__ int   snbr[256*K27];
  __shared__ float sstat[64];
  int tid  = threadIdx.x;
  int base = blockIdx.x*256;
  for (int i = tid; i < 256*K27; i += 256){
    int v = base + i / K27;
    snbr[i] = (v < NVOX) ? nbr[base*K27 + i] : NVOX;
  }
  if (tid < 64) sstat[tid] = 0.f;
  __syncthreads();

  int l = tid & 63, w = tid >> 6;
  int g = l >> 4, r16 = l & 15;
  const int vb = w*64;

  bf16x8 B[4][2];
  #pragma unroll
  for (int kb = 0; kb < 4; ++kb)
    #pragma unroll
    for (int h = 0; h < 2; ++h)
      B[kb][h] = *reinterpret_cast<const bf16x8*>(pw0 + (kb*2 + h)*512 + l*8);

  f32x4 acc[4][2];
  #pragma unroll
  for (int t = 0; t < 4; ++t)
    #pragma unroll
    for (int h = 0; h < 2; ++h)
      acc[t][h] = (f32x4){0.f,0.f,0.f,0.f};

  #pragma unroll
  for (int t = 0; t < 4; ++t){
    int row = (vb + t*16 + r16)*K27;
    #pragma unroll
    for (int kb = 0; kb < 4; ++kb){
      int tap0 = kb*8 + g*2;
      int tap1 = tap0 + 1;
      int i0 = (tap0 < K27) ? tap0 : 0;
      int i1 = (tap1 < K27) ? tap1 : 0;
      int j0 = snbr[row + i0]; if (tap0 >= K27) j0 = NVOX;
      int j1 = snbr[row + i1]; if (tap1 >= K27) j1 = NVOX;
      float4 v0 = fpad[j0];
      float4 v1 = fpad[j1];
      ushort8 au;
      au[0] = f2bf(v0.x); au[1] = f2bf(v0.y); au[2] = f2bf(v0.z); au[3] = 0;
      au[4] = f2bf(v1.x); au[5] = f2bf(v1.y); au[6] = f2bf(v1.z); au[7] = 0;
      bf16x8 a = __builtin_bit_cast(bf16x8, au);
      acc[t][0] = __builtin_amdgcn_mfma_f32_16x16x32_bf16(a, B[kb][0], acc[t][0], 0, 0, 0);
      acc[t][1] = __builtin_amdgcn_mfma_f32_16x16x32_bf16(a, B[kb][1], acc[t][1], 0, 0, 0);
    }
  }

  float s0[2] = {0.f, 0.f}, s1[2] = {0.f, 0.f};
  #pragma unroll
  for (int t = 0; t < 4; ++t){
    #pragma unroll
    for (int r = 0; r < 4; ++r){
      int row = base + vb + t*16 + g*4 + r;
      if (row < NVOX){
        #pragma unroll
        for (int h = 0; h < 2; ++h){
          float v = acc[t][h][r];
          trunk[(size_t)row*32 + h*16 + r16] = v;
          s0[h] += v; s1[h] += v*v;
        }
      }
    }
  }
  #pragma unroll
  for (int h = 0; h < 2; ++h){
    s0[h] += __shfl_xor(s0[h], 16);
    s0[h] += __shfl_xor(s0[h], 32);
    s1[h] += __shfl_xor(s1[h], 16);
    s1[h] += __shfl_xor(s1[h], 32);
  }
  if (l < 16){
    atomicAdd(&sstat[r16],      s0[0]);
    atomicAdd(&sstat[32 + r16], s1[0]);
    atomicAdd(&sstat[16 + r16], s0[1]);
    atomicAdd(&sstat[48 + r16], s1[1]);
  }
  __syncthreads();
  if (tid < 64) atomicAdd(&stats[(blockIdx.x & 63)*64 + tid], sstat[tid]);
}

// ---- activation with inline BN finalize: bf16 act = relu(bn(trunk)); row N zeroed ----
__global__ void __launch_bounds__(256) act_kernel(
    const float* __restrict__ trunk, const float* __restrict__ stats,
    const float* __restrict__ g, const float* __restrict__ b,
    unsigned short* __restrict__ act){
  __shared__ float sbnp[64];
  int tid = threadIdx.x;
  if (tid < 32){
    float s = 0.f, q = 0.f;
    for (int i = 0; i < 64; ++i){ s += stats[i*64 + tid]; q += stats[i*64 + 32 + tid]; }
    float inv = 1.0f / (float)NVOX;
    float mu  = s * inv;
    float var = q * inv - mu*mu;
    float sc  = g[tid] * rsqrtf(var + 1e-4f);
    sbnp[tid]      = sc;
    sbnp[32 + tid] = b[tid] - mu*sc;
  }
  __syncthreads();

  int t = blockIdx.x*256 + tid;
  if (t >= (NVOX+1)*4) return;
  int row = t >> 2, part = t & 3;
  ushort8 o;
  if (row < NVOX){
    const float* p = trunk + (size_t)row*32 + part*8;
    #pragma unroll
    for (int i = 0; i < 8; ++i){
      float v = p[i]*sbnp[part*8 + i] + sbnp[32 + part*8 + i];
      v = fmaxf(v, 0.f);
      o[i] = f2bf(v);
    }
  } else {
    #pragma unroll
    for (int i = 0; i < 8; ++i) o[i] = 0;
  }
  *reinterpret_cast<ushort8*>(act + (size_t)row*32 + part*8) = o;
}

// ---- MFMA conv 32->32 over 27 taps, k+1 register prefetch; optional residual; fused stats ----
template<bool RES>
__global__ void __launch_bounds__(256) conv_mfma_kernel(
    const unsigned short* __restrict__ act, const int* __restrict__ nbr,
    const unsigned short* __restrict__ pw, float* __restrict__ trunk,
    float* __restrict__ stats){
  __shared__ int   snbr[256*K27];
  __shared__ float sstat[64];
  int tid  = threadIdx.x;
  int base = blockIdx.x*256;
  for (int i = tid; i < 256*K27; i += 256){
    int v = base + i / K27;
    snbr[i] = (v < NVOX) ? nbr[base*K27 + i] : NVOX;
  }
  if (tid < 64) sstat[tid] = 0.f;
  __syncthreads();

  int l = tid & 63, w = tid >> 6;
  int g = l >> 4, r16 = l & 15;
  const int vb = w*64;
  const int rb0 = (vb      + r16)*K27;
  const int rb1 = (vb + 16 + r16)*K27;
  const int rb2 = (vb + 32 + r16)*K27;
  const int rb3 = (vb + 48 + r16)*K27;

  f32x4 acc[4][2];
  #pragma unroll
  for (int t = 0; t < 4; ++t)
    #pragma unroll
    for (int h = 0; h < 2; ++h)
      acc[t][h] = (f32x4){0.f,0.f,0.f,0.f};

  // prologue: k=0 loads
  bf16x8 nb0 = *reinterpret_cast<const bf16x8*>(pw + l*8);
  bf16x8 nb1 = *reinterpret_cast<const bf16x8*>(pw + 512 + l*8);
  bf16x8 na0, na1, na2, na3;
  {
    int j0 = snbr[rb0], j1 = snbr[rb1], j2 = snbr[rb2], j3 = snbr[rb3];
    na0 = *reinterpret_cast<const bf16x8*>(act + (size_t)j0*32 + g*8);
    na1 = *reinterpret_cast<const bf16x8*>(act + (size_t)j1*32 + g*8);
    na2 = *reinterpret_cast<const bf16x8*>(act + (size_t)j2*32 + g*8);
    na3 = *reinterpret_cast<const bf16x8*>(act + (size_t)j3*32 + g*8);
  }

  #pragma unroll
  for (int k = 0; k < K27; ++k){
    bf16x8 b0 = nb0, b1 = nb1;
    bf16x8 a0 = na0, a1 = na1, a2 = na2, a3 = na3;
    if (k + 1 < K27){
      nb0 = *reinterpret_cast<const bf16x8*>(pw + ((k+1)*2    )*512 + l*8);
      nb1 = *reinterpret_cast<const bf16x8*>(pw + ((k+1)*2 + 1)*512 + l*8);
      int j0 = snbr[rb0 + k+1], j1 = snbr[rb1 + k+1], j2 = snbr[rb2 + k+1], j3 = snbr[rb3 + k+1];
      na0 = *reinterpret_cast<const bf16x8*>(act + (size_t)j0*32 + g*8);
      na1 = *reinterpret_cast<const bf16x8*>(act + (size_t)j1*32 + g*8);
      na2 = *reinterpret_cast<const bf16x8*>(act + (size_t)j2*32 + g*8);
      na3 = *reinterpret_cast<const bf16x8*>(act + (size_t)j3*32 + g*8);
    }
    acc[0][0] = __builtin_amdgcn_mfma_f32_16x16x32_bf16(a0, b0, acc[0][0], 0, 0, 0);
    acc[0][1] = __builtin_amdgcn_mfma_f32_16x16x32_bf16(a0, b1, acc[0][1], 0, 0, 0);
    acc[1][0] = __builtin_amdgcn_mfma_f32_16x16x32_bf16(a1, b0, acc[1][0], 0, 0, 0);
    acc[1][1] = __builtin_amdgcn_mfma_f32_16x16x32_bf16(a1, b1, acc[1][1], 0, 0, 0);
    acc[2][0] = __builtin_amdgcn_mfma_f32_16x16x32_bf16(a2, b0, acc[2][0], 0, 0, 0);
    acc[2][1] = __builtin_amdgcn_mfma_f32_16x16x32_bf16(a2, b1, acc[2][1], 0, 0, 0);
    acc[3][0] = __builtin_amdgcn_mfma_f32_16x16x32_bf16(a3, b0, acc[3][0], 0, 0, 0);
    acc[3][1] = __builtin_amdgcn_mfma_f32_16x16x32_bf16(a3, b1, acc[3][1], 0, 0, 0);
  }

  float s0[2] = {0.f, 0.f}, s1[2] = {0.f, 0.f};
  #pragma unroll
  for (int t = 0; t < 4; ++t){
    #pragma unroll
    for (int r = 0; r < 4; ++r){
      int row = base + vb + t*16 + g*4 + r;
      if (row < NVOX){
        #pragma unroll
        for (int h = 0; h < 2; ++h){
          float v = acc[t][h][r];
          float* p = trunk + (size_t)row*32 + h*16 + r16;
          if (RES) v += *p;
          *p = v;
          s0[h] += v; s1[h] += v*v;
        }
      }
    }
  }
  #pragma unroll
  for (int h = 0; h < 2; ++h){
    s0[h] += __shfl_xor(s0[h], 16);
    s0[h] += __shfl_xor(s0[h], 32);
    s1[h] += __shfl_xor(s1[h], 16);
    s1[h] += __shfl_xor(s1[h], 32);
  }
  if (l < 16){
    atomicAdd(&sstat[r16],      s0[0]);
    atomicAdd(&sstat[32 + r16], s1[0]);
    atomicAdd(&sstat[16 + r16], s0[1]);
    atomicAdd(&sstat[48 + r16], s1[1]);
  }
  __syncthreads();
  if (tid < 64) atomicAdd(&stats[(blockIdx.x & 63)*64 + tid], sstat[tid]);
}

// ---- MFMA heads with inline final-BN ----
__global__ void __launch_bounds__(256) heads_mfma_kernel(
    const float* __restrict__ trunk, const float* __restrict__ stats,
    const float* __restrict__ gf, const float* __restrict__ bf,
    const unsigned short* __restrict__ pwh, const float* __restrict__ bcat,
    const float* __restrict__ b_le, const float* __restrict__ w_lr, const float* __restrict__ b_lr,
    float* __restrict__ out){
  __shared__ float lds[4][16][33];
  __shared__ float sbnp[64];
  int tid = threadIdx.x;
  if (tid < 32){
    float s = 0.f, q = 0.f;
    for (int i = 0; i < 64; ++i){ s += stats[i*64 + tid]; q += stats[i*64 + 32 + tid]; }
    float inv = 1.0f / (float)NVOX;
    float mu  = s * inv;
    float var = q * inv - mu*mu;
    float sc  = gf[tid] * rsqrtf(var + 1e-4f);
    sbnp[tid]      = sc;
    sbnp[32 + tid] = bf[tid] - mu*sc;
  }
  __syncthreads();

  int l = tid & 63, w = tid >> 6;
  int g = l >> 4, r16 = l & 15;
  int base = blockIdx.x*256 + w*64;

  bf16x8 B1[6], B2[2];
  #pragma unroll
  for (int f = 0; f < 6; ++f)
    B1[f] = *reinterpret_cast<const bf16x8*>(pwh + f*512 + l*8);
  #pragma unroll
  for (int h = 0; h < 2; ++h)
    B2[h] = *reinterpret_cast<const bf16x8*>(pwh + (6+h)*512 + l*8);

  float sc[8], bi[8];
  #pragma unroll
  for (int i = 0; i < 8; ++i){ sc[i] = sbnp[g*8 + i]; bi[i] = sbnp[32 + g*8 + i]; }
  float wlr0 = w_lr[r16], wlr1 = w_lr[16 + r16];
  float blr  = b_lr[0];
  float bc0  = bcat[r16],      bc1  = bcat[16 + r16];   // b_fe
  float bc2  = bcat[32 + r16], bc3  = bcat[48 + r16];   // b_fr
  float bc4  = bcat[64 + r16], bc5  = bcat[80 + r16];   // b_cls (padded)
  float ble0 = b_le[r16],      ble1 = b_le[16 + r16];

  float* out_e = out + (size_t)NVOX*20;
  float* out_o = out + (size_t)NVOX*52;

  for (int t = 0; t < 4; ++t){
    int arow = base + t*16 + r16;
    float4 fa = {0.f,0.f,0.f,0.f}, fb2 = {0.f,0.f,0.f,0.f};
    if (arow < NVOX){
      fa  = *reinterpret_cast<const float4*>(trunk + (size_t)arow*32 + g*8);
      fb2 = *reinterpret_cast<const float4*>(trunk + (size_t)arow*32 + g*8 + 4);
    }
    ushort8 au;
    au[0] = f2bf(fmaxf(fa.x*sc[0] + bi[0], 0.f));
    au[1] = f2bf(fmaxf(fa.y*sc[1] + bi[1], 0.f));
    au[2] = f2bf(fmaxf(fa.z*sc[2] + bi[2], 0.f));
    au[3] = f2bf(fmaxf(fa.w*sc[3] + bi[3], 0.f));
    au[4] = f2bf(fmaxf(fb2.x*sc[4] + bi[4], 0.f));
    au[5] = f2bf(fmaxf(fb2.y*sc[5] + bi[5], 0.f));
    au[6] = f2bf(fmaxf(fb2.z*sc[6] + bi[6], 0.f));
    au[7] = f2bf(fmaxf(fb2.w*sc[7] + bi[7], 0.f));
    bf16x8 a = __builtin_bit_cast(bf16x8, au);

    f32x4 acc[6];
    #pragma unroll
    for (int j = 0; j < 6; ++j){
      acc[j] = (f32x4){0.f,0.f,0.f,0.f};
      acc[j] = __builtin_amdgcn_mfma_f32_16x16x32_bf16(a, B1[j], acc[j], 0, 0, 0);
    }

    #pragma unroll
    for (int r = 0; r < 4; ++r){
      int orow = base + t*16 + g*4 + r;
      if (orow < NVOX){
        out[(size_t)orow*20 + r16] = acc[4][r] + bc4;           // cls 0..15
        if (r16 < 4)
          out[(size_t)orow*20 + 16 + r16] = acc[5][r] + bc5;    // cls 16..19
      }
    }

    float part[4];
    #pragma unroll
    for (int r = 0; r < 4; ++r)
      part[r] = (acc[2][r] + bc2)*wlr0 + (acc[3][r] + bc3)*wlr1;
    #pragma unroll
    for (int r = 0; r < 4; ++r){
      part[r] += __shfl_xor(part[r], 1);
      part[r] += __shfl_xor(part[r], 2);
      part[r] += __shfl_xor(part[r], 4);
      part[r] += __shfl_xor(part[r], 8);
    }
    if (r16 == 0){
      #pragma unroll
      for (int r = 0; r < 4; ++r){
        int orow = base + t*16 + g*4 + r;
        if (orow < NVOX)
          out_o[orow] = 1.f/(1.f + __expf(-(part[r] + blr)));
      }
    }

    #pragma unroll
    for (int r = 0; r < 4; ++r){
      lds[w][g*4 + r][r16]      = acc[0][r] + bc0;
      lds[w][g*4 + r][16 + r16] = acc[1][r] + bc1;
    }
    __syncthreads();
    ushort8 a2u;
    #pragma unroll
    for (int i = 0; i < 8; ++i)
      a2u[i] = f2bf(lds[w][r16][g*8 + i]);
    bf16x8 a2 = __builtin_bit_cast(bf16x8, a2u);
    f32x4 e0 = (f32x4){0.f,0.f,0.f,0.f}, e1 = (f32x4){0.f,0.f,0.f,0.f};
    e0 = __builtin_amdgcn_mfma_f32_16x16x32_bf16(a2, B2[0], e0, 0, 0, 0);
    e1 = __builtin_amdgcn_mfma_f32_16x16x32_bf16(a2, B2[1], e1, 0, 0, 0);
    #pragma unroll
    for (int r = 0; r < 4; ++r){
      int orow = base + t*16 + g*4 + r;
      if (orow < NVOX){
        out_e[(size_t)orow*32 + r16]      = e0[r] + ble0;
        out_e[(size_t)orow*32 + 16 + r16] = e1[r] + ble1;
      }
    }
    __syncthreads();
  }
}

extern "C" void kernel_launch(void* const* d_in, const int* in_sizes, int n_in,
                              void* d_out, int out_size, void* d_ws, size_t ws_size,
                              hipStream_t stream){
  const float* features = (const float*)d_in[0];
  const int*   nbr      = (const int*)  d_in[1];
  const float* w0       = (const float*)d_in[2];
  const float* bw       = (const float*)d_in[3];
  const float* bg       = (const float*)d_in[4];
  const float* bb       = (const float*)d_in[5];
  const float* gf       = (const float*)d_in[6];
  const float* bf       = (const float*)d_in[7];
  const float* w_cls    = (const float*)d_in[8];
  const float* b_cls    = (const float*)d_in[9];
  const float* w_fe     = (const float*)d_in[10];
  const float* b_fe     = (const float*)d_in[11];
  const float* w_le     = (const float*)d_in[12];
  const float* b_le     = (const float*)d_in[13];
  const float* w_fr     = (const float*)d_in[14];
  const float* b_fr     = (const float*)d_in[15];
  const float* w_lr     = (const float*)d_in[16];
  const float* b_lr     = (const float*)d_in[17];
  float* out = (float*)d_out;

  char* ws = (char*)d_ws;
  float*          trunkA = (float*)(ws);                       // [N][32] f32
  float*          trunkH = (float*)(ws + 38400000);            // [N][32] f32
  float4*         fpad   = (float4*)(ws + 38400000);           // [N+1][4] f32 (dead before conv1 writes trunkH)
  unsigned short* actB   = (unsigned short*)(ws + 76800000);   // [(N+1)][32] bf16
  unsigned short* pw     = (unsigned short*)(ws + 96000128);   // packed conv weights (221184 B)
  unsigned short* pw0    = (unsigned short*)(ws + 96221312);   // packed conv0 weights (8192 B)
  float*          stats  = (float*)(ws + 96229504);            // 5 x 64 slots x 64 (81920 B)
  unsigned short* pwh    = (unsigned short*)(ws + 96311424);   // packed head weights (8192 B)
  float*          bcat   = (float*)(ws + 96319616);            // 96 f32 head biases

  hipMemsetAsync(stats, 0, 5*64*64*sizeof(float), stream);
  pack_w_kernel<<<(4*K27*2*64 + 4*2*64 + 255)/256, 256, 0, stream>>>(bw, w0, pw, pw0);
  pack_hw_kernel<<<1, 512, 0, stream>>>(w_cls, b_cls, w_fe, b_fe, w_le, w_fr, b_fr, pwh, bcat);
  prepad_kernel<<<(NVOX + 256)/256, 256, 0, stream>>>(features, fpad);

  const int NB = (NVOX + 255)/256;
  const int NA = ((NVOX+1)*4 + 255)/256;

  conv0_mfma_kernel<<<NB, 256, 0, stream>>>(fpad, nbr, pw0, trunkA, stats + 0*4096);
  act_kernel<<<NA, 256, 0, stream>>>(trunkA, stats + 0*4096, bg +  0, bb +  0, actB);
  conv_mfma_kernel<false><<<NB, 256, 0, stream>>>(actB, nbr, pw + 0*27648, trunkH, stats + 1*4096);
  act_kernel<<<NA, 256, 0, stream>>>(trunkH, stats + 1*4096, bg + 32, bb + 32, actB);
  conv_mfma_kernel<true ><<<NB, 256, 0, stream>>>(actB, nbr, pw + 1*27648, trunkA, stats + 2*4096);
  act_kernel<<<NA, 256, 0, stream>>>(trunkA, stats + 2*4096, bg + 64, bb + 64, actB);
  conv_mfma_kernel<false><<<NB, 256, 0, stream>>>(actB, nbr, pw + 2*27648, trunkH, stats + 3*4096);
  act_kernel<<<NA, 256, 0, stream>>>(trunkH, stats + 3*4096, bg + 96, bb + 96, actB);
  conv_mfma_kernel<true ><<<NB, 256, 0, stream>>>(actB, nbr, pw + 3*27648, trunkA, stats + 4*4096);
  heads_mfma_kernel<<<NB, 256, 0, stream>>>(trunkA, stats + 4*4096, gf, bf, pwh, bcat,
                                            b_le, w_lr, b_lr, out);
}